// Round 14
// baseline (472.888 us; speedup 1.0000x reference)
//
#include <hip/hip_runtime.h>
#include <hip/hip_bf16.h>

// Problem constants
#define EMBD   1024
#define NHEAD  16
#define HDIM   64
#define SEQ    2048
#define BATCH  2
#define MROWS  4096          // BATCH*SEQ
#define NQKV   3072          // 3*EMBD
#define VSTR   2064          // padded vtT row stride (breaks 4KB L2 aliasing)

using floatx4 = __attribute__((ext_vector_type(4))) float;
using short8  = __attribute__((ext_vector_type(8))) short;

static __device__ __forceinline__ float bf2f(unsigned short u) {
    unsigned int v = ((unsigned int)u) << 16;
    return __uint_as_float(v);
}
static __device__ __forceinline__ unsigned short f2bf(float f) {
    __hip_bfloat16 h = __float2bfloat16(f);   // RNE
    return *reinterpret_cast<unsigned short*>(&h);
}

// ---------------------------------------------------------------------------
// Cast kernels: x -> split bf16 (hi + lo); w -> bf16, transposed to [N][K].
// ---------------------------------------------------------------------------
__global__ __launch_bounds__(256) void cast_x(
    const float* __restrict__ x, unsigned short* __restrict__ xh,
    unsigned short* __restrict__ xl)
{
    int idx = (blockIdx.x * 256 + threadIdx.x) * 4;
    float4 v = *(const float4*)(x + idx);
    ushort4 h, l;
    h.x = f2bf(v.x); l.x = f2bf(v.x - bf2f(h.x));
    h.y = f2bf(v.y); l.y = f2bf(v.y - bf2f(h.y));
    h.z = f2bf(v.z); l.z = f2bf(v.z - bf2f(h.z));
    h.w = f2bf(v.w); l.w = f2bf(v.w - bf2f(h.w));
    *(ushort4*)(xh + idx) = h;
    *(ushort4*)(xl + idx) = l;
}

// w [1024][N] fp32 -> wT [N][1024] bf16 (64x64 LDS-tiled transpose)
__global__ __launch_bounds__(256) void cast_wT(
    const float* __restrict__ w, unsigned short* __restrict__ wT, int N)
{
    __shared__ unsigned short th[64][65];
    const int k0 = blockIdx.y * 64, n0 = blockIdx.x * 64;
    const int t = threadIdx.x;
    const int r = t >> 4, c = (t & 15) * 4;
    for (int rr = r; rr < 64; rr += 16) {
        float4 v = *(const float4*)(w + (size_t)(k0 + rr) * N + n0 + c);
        th[rr][c + 0] = f2bf(v.x);
        th[rr][c + 1] = f2bf(v.y);
        th[rr][c + 2] = f2bf(v.z);
        th[rr][c + 3] = f2bf(v.w);
    }
    __syncthreads();
    for (int rr = r; rr < 64; rr += 16) {
        ushort4 h;
        h.x = th[c + 0][rr]; h.y = th[c + 1][rr];
        h.z = th[c + 2][rr]; h.w = th[c + 3][rr];
        *(ushort4*)(wT + (size_t)(n0 + rr) * 1024 + k0 + c) = h;
    }
}

// ---------------------------------------------------------------------------
// qkv = x @ w_qkv via split-x bf16 MFMA (xh.wb + xl.wb), fused RoPE.
// v14: REG-STAGED LDS (T14 split; the one staging variant untried).
// Each byte fetched ONCE per block (was twice): 6x16B global loads/thread
// per K-step -> ds_write_b128 -> barrier -> frag ds_read + 32 MFMA.
// Next step's loads issue BEFORE the MFMA block; pinned by keepalive on
// only 6 regs (24 VGPR -- fits, unlike R12's 28-frag spill).  gl_lds is
// NOT used (R7/R8 pathology).  Numerics identical to R9.
// Two barriers/K-step: (1) prev reads done before overwrite, (2) writes
// visible before reads.  LDS 24 KB single-buffered.
// ---------------------------------------------------------------------------
__global__ __launch_bounds__(256, 1) void gemm_qkv_mfma(
    const unsigned short* __restrict__ xh, const unsigned short* __restrict__ xl,
    const unsigned short* __restrict__ wbT,
    unsigned short* __restrict__ qst, unsigned short* __restrict__ kst,
    unsigned short* __restrict__ vtT)
{
    __shared__ __attribute__((aligned(16))) unsigned short sAh[128][32];
    __shared__ __attribute__((aligned(16))) unsigned short sAl[128][32];
    __shared__ __attribute__((aligned(16))) unsigned short sB [128][32];

    const int t = threadIdx.x, wave = t >> 6, lane = t & 63;
    const int col = lane & 15, quad = lane >> 4;
    const int n0 = blockIdx.x * 128;
    const int m0 = blockIdx.y * 128;
    const int which = n0 >> 10;              // block-uniform: 0=q,1=k,2=v
    const int wm = (wave >> 1) * 64, wn = (wave & 1) * 64;

    floatx4 acc[4][4];
    #pragma unroll
    for (int i = 0; i < 4; ++i)
        #pragma unroll
        for (int j = 0; j < 4; ++j) acc[i][j] = (floatx4){0.f, 0.f, 0.f, 0.f};

    // staging geometry: thread t covers rows {srow, srow+64} at k-cols scol..+8
    const int srow = t >> 2;                 // 0..63
    const int scol = (t & 3) * 8;            // 0,8,16,24
    const unsigned short* gAh0 = xh  + (size_t)(m0 + srow) * 1024 + scol;
    const unsigned short* gAh1 = xh  + (size_t)(m0 + 64 + srow) * 1024 + scol;
    const unsigned short* gAl0 = xl  + (size_t)(m0 + srow) * 1024 + scol;
    const unsigned short* gAl1 = xl  + (size_t)(m0 + 64 + srow) * 1024 + scol;
    const unsigned short* gB0  = wbT + (size_t)(n0 + srow) * 1024 + scol;
    const unsigned short* gB1  = wbT + (size_t)(n0 + 64 + srow) * 1024 + scol;

    short8 rh0, rh1, rl0, rl1, rb0, rb1;     // staging registers (6 x 16B)

#define LOADSTAGE(K0) do {                                                        \
        rh0 = *(const short8*)(gAh0 + (K0));                                      \
        rh1 = *(const short8*)(gAh1 + (K0));                                      \
        rl0 = *(const short8*)(gAl0 + (K0));                                      \
        rl1 = *(const short8*)(gAl1 + (K0));                                      \
        rb0 = *(const short8*)(gB0  + (K0));                                      \
        rb1 = *(const short8*)(gB1  + (K0));                                      \
    } while (0)

#define WRITESTAGE() do {                                                         \
        *(short8*)&sAh[srow][scol]      = rh0;                                    \
        *(short8*)&sAh[64 + srow][scol] = rh1;                                    \
        *(short8*)&sAl[srow][scol]      = rl0;                                    \
        *(short8*)&sAl[64 + srow][scol] = rl1;                                    \
        *(short8*)&sB [srow][scol]      = rb0;                                    \
        *(short8*)&sB [64 + srow][scol] = rb1;                                    \
    } while (0)

    LOADSTAGE(0);
    for (int k0 = 0; k0 < 1024; k0 += 32) {
        __syncthreads();                     // all waves done reading LDS
        WRITESTAGE();
        __syncthreads();                     // staged tile visible
        if (k0 + 32 < 1024) {
            LOADSTAGE(k0 + 32);              // issue next loads EARLY
            // keepalive: anchor the 6 loads here (IR-level); tiny reg cost
            asm volatile("" : "+v"(rh0), "+v"(rh1), "+v"(rl0),
                              "+v"(rl1), "+v"(rb0), "+v"(rb1));
        }

        short8 bf[4], ah[4], al[4];
        #pragma unroll
        for (int f = 0; f < 4; ++f) {
            bf[f] = *(const short8*)&sB [wn + f * 16 + col][quad * 8];
            ah[f] = *(const short8*)&sAh[wm + f * 16 + col][quad * 8];
            al[f] = *(const short8*)&sAl[wm + f * 16 + col][quad * 8];
        }

        if (which < 2) {
            #pragma unroll
            for (int fm = 0; fm < 4; ++fm)
                #pragma unroll
                for (int fn = 0; fn < 4; ++fn) {
                    acc[fm][fn] = __builtin_amdgcn_mfma_f32_16x16x32_bf16(
                        bf[fn], ah[fm], acc[fm][fn], 0, 0, 0);   // C^T
                    acc[fm][fn] = __builtin_amdgcn_mfma_f32_16x16x32_bf16(
                        bf[fn], al[fm], acc[fm][fn], 0, 0, 0);
                }
        } else {
            #pragma unroll
            for (int fm = 0; fm < 4; ++fm)
                #pragma unroll
                for (int fn = 0; fn < 4; ++fn) {
                    acc[fm][fn] = __builtin_amdgcn_mfma_f32_16x16x32_bf16(
                        ah[fm], bf[fn], acc[fm][fn], 0, 0, 0);
                    acc[fm][fn] = __builtin_amdgcn_mfma_f32_16x16x32_bf16(
                        al[fm], bf[fn], acc[fm][fn], 0, 0, 0);
                }
        }
    }
#undef LOADSTAGE
#undef WRITESTAGE

    const float RLOG = 9.210340371976184f / 32.0f;   // ln(10000)/32
    if (which < 2) {
        unsigned short* dst = (which == 0) ? qst : kst;
        const float scale = (which == 0) ? 0.125f : 1.0f;   // D^-0.5 folded into q
        #pragma unroll
        for (int fm = 0; fm < 4; ++fm) {
            const int s_g = m0 + wm + fm * 16 + col;     // C^T col = x row = s
            const int b = s_g >> 11, s = s_g & 2047;
            const float sf = (float)s;
            #pragma unroll
            for (int fn = 0; fn < 4; ++fn) {
                const int nl = (n0 & 1023) + wn + fn * 16 + quad * 4;  // C^T row = w col
                const int h = nl >> 6;
                const int d0 = nl & 63;                  // multiple of 4
                floatx4 c = acc[fm][fn];
                float o_[4];
                #pragma unroll
                for (int pp = 0; pp < 2; ++pp) {
                    int de = d0 + pp * 2;                // even
                    float fe = __expf(-(float)(de & 31) * RLOG);
                    float fo = __expf(-(float)((de + 1) & 31) * RLOG);
                    float se, ce, so, co;
                    sincosf(sf * fe, &se, &ce);
                    sincosf(sf * fo, &so, &co);
                    float qe = c[pp * 2], qo = c[pp * 2 + 1];
                    o_[pp * 2]     = (qe * ce - qo * se) * scale;
                    o_[pp * 2 + 1] = (qo * co + qe * so) * scale;
                }
                ushort4 o4;
                o4.x = f2bf(o_[0]); o4.y = f2bf(o_[1]);
                o4.z = f2bf(o_[2]); o4.w = f2bf(o_[3]);
                *(ushort4*)(dst + ((size_t)(b * 16 + h) * 2048 + s) * 64 + d0) = o4;
            }
        }
    } else {
        #pragma unroll
        for (int fm = 0; fm < 4; ++fm) {
            const int m = m0 + wm + fm * 16 + quad * 4;  // 4 consecutive s (regs)
            const int b = m >> 11, s0 = m & 2047;
            #pragma unroll
            for (int fn = 0; fn < 4; ++fn) {
                const int nl = (n0 & 1023) + wn + fn * 16 + col;
                const int h = nl >> 6;
                const int d = nl & 63;
                floatx4 c = acc[fm][fn];
                ushort4 o4;
                o4.x = f2bf(c[0]); o4.y = f2bf(c[1]);
                o4.z = f2bf(c[2]); o4.w = f2bf(c[3]);
                *(ushort4*)(vtT + (size_t)(b * 16 + h) * 64 * VSTR
                                + (size_t)d * VSTR + s0) = o4;
            }
        }
    }
}

// ---------------------------------------------------------------------------
// Attention (R4/R9-proven): 2 q-tiles per wave, key-split 4 waves, padded
// p_tile, depth-1 K/V register prefetch.
// Block: 4 key-split waves x 32 rows.  Grid: 32 bh x 64 = 2048 blocks.
// ---------------------------------------------------------------------------
__global__ __launch_bounds__(256) void attn_mfma(
    const unsigned short* __restrict__ qst,
    const unsigned short* __restrict__ kst,
    const unsigned short* __restrict__ vtT,
    unsigned short* __restrict__ attn)
{
    __shared__ __attribute__((aligned(16))) unsigned short p_tile[2][4][16][40];
    __shared__ float4 redbuf[3][64][2][5];         // waves 1..3 partials x 2 tiles

    const int tid  = threadIdx.x;
    const int wave = tid >> 6;
    const int lane = tid & 63;
    const int col  = lane & 15;
    const int quad = lane >> 4;

    const int bh   = blockIdx.x >> 6;              // 0..31
    const int row0 = (blockIdx.x & 63) * 32;       // 32-row unit (2 tiles)

    const size_t base  = (size_t)bh * SEQ * HDIM;
    const size_t vbase = (size_t)bh * HDIM * VSTR;

    // Q fragments for both tiles
    short8 aq[2][2];
    #pragma unroll
    for (int tt = 0; tt < 2; ++tt) {
        const unsigned short* qp = qst + base
            + (size_t)(row0 + tt * 16 + col) * HDIM + quad * 8;
        aq[tt][0] = *(const short8*)(qp);
        aq[tt][1] = *(const short8*)(qp + 32);
    }

    int iR[2][4], ngR[2][4], j0R[2][4];
    #pragma unroll
    for (int tt = 0; tt < 2; ++tt)
        #pragma unroll
        for (int r = 0; r < 4; ++r) {
            int i = row0 + tt * 16 + quad * 4 + r;
            iR[tt][r] = i;
            ngR[tt][r] = (i + 1 < 4) ? (i + 1) : 4;
            int L = i - 128;
            int bs = (i >> 8) << 8;
            if (bs < L) L = bs;
            if (L < 0) L = 0;
            j0R[tt][r] = (L > 4) ? L : 4;
        }

    floatx4 o[2][4];
    float lsum[2][4];
    #pragma unroll
    for (int tt = 0; tt < 2; ++tt)
        #pragma unroll
        for (int r = 0; r < 4; ++r) {
            o[tt][r] = (floatx4){0.f, 0.f, 0.f, 0.f};
            lsum[tt][r] = 0.f;
        }

    const int kbeg = wave * (SEQ / 4);             // 512 keys per wave

    // Double-buffered K/V fragments (indices static after full unroll).
    short8 kf[2][4];   // [buf][h16*2 + half]: K[kc+h16*16+col][quad*8 + half*32..]
    short8 vf[2][4];   // [buf][dt]:           V^T[d=col+16dt][kc+quad*8..]

#define LOADK(B, IT) do {                                                         \
        const int kc_ = kbeg + (IT) * 32;                                         \
        const unsigned short* kp_ = kst + base + (size_t)(kc_ + col) * HDIM       \
                                        + quad * 8;                               \
        kf[B][0] = *(const short8*)(kp_);                                         \
        kf[B][1] = *(const short8*)(kp_ + 32);                                    \
        kf[B][2] = *(const short8*)(kp_ + 16 * HDIM);                             \
        kf[B][3] = *(const short8*)(kp_ + 16 * HDIM + 32);                        \
    } while (0)
#define LOADV(B, IT) do {                                                         \
        const int kc_ = kbeg + (IT) * 32;                                         \
        const unsigned short* vp_ = vtT + vbase + (size_t)col * VSTR              \
                                        + kc_ + quad * 8;                         \
        vf[B][0] = *(const short8*)(vp_);                                         \
        vf[B][1] = *(const short8*)(vp_ + 16 * VSTR);                             \
        vf[B][2] = *(const short8*)(vp_ + 32 * VSTR);                             \
        vf[B][3] = *(const short8*)(vp_ + 48 * VSTR);                             \
    } while (0)

    LOADK(0, 0);
    LOADV(0, 0);
    #pragma unroll
    for (int it = 0; it < 16; ++it) {
        const int cur = it & 1;                    // compile-time after unroll
        if (it < 15) { LOADK(cur ^ 1, it + 1); LOADV(cur ^ 1, it + 1); }
        __builtin_amdgcn_sched_barrier(0);         // pin prefetch before compute

        const int kc0 = kbeg + it * 32;
        #pragma unroll
        for (int h16 = 0; h16 < 2; ++h16) {
            const int j = kc0 + h16 * 16 + col;
            #pragma unroll
            for (int tt = 0; tt < 2; ++tt) {
                floatx4 s = {0.f, 0.f, 0.f, 0.f};
                s = __builtin_amdgcn_mfma_f32_16x16x32_bf16(
                        aq[tt][0], kf[cur][h16 * 2 + 0], s, 0, 0, 0);
                s = __builtin_amdgcn_mfma_f32_16x16x32_bf16(
                        aq[tt][1], kf[cur][h16 * 2 + 1], s, 0, 0, 0);
                #pragma unroll
                for (int r = 0; r < 4; ++r) {
                    bool excl = (j < ngR[tt][r]) || (j >= j0R[tt][r] && j <= iR[tt][r]);
                    float p = excl ? 0.f : __expf(s[r]);
                    lsum[tt][r] += p;
                    p_tile[tt][wave][quad * 4 + r][h16 * 16 + col] = f2bf(p);
                }
            }
        }
        // wave-private LDS slices: no barrier (lgkmcnt-ordered)
        #pragma unroll
        for (int tt = 0; tt < 2; ++tt) {
            short8 ap = *(const short8*)&p_tile[tt][wave][col][quad * 8];
            o[tt][0] = __builtin_amdgcn_mfma_f32_16x16x32_bf16(ap, vf[cur][0], o[tt][0], 0, 0, 0);
            o[tt][1] = __builtin_amdgcn_mfma_f32_16x16x32_bf16(ap, vf[cur][1], o[tt][1], 0, 0, 0);
            o[tt][2] = __builtin_amdgcn_mfma_f32_16x16x32_bf16(ap, vf[cur][2], o[tt][2], 0, 0, 0);
            o[tt][3] = __builtin_amdgcn_mfma_f32_16x16x32_bf16(ap, vf[cur][3], o[tt][3], 0, 0, 0);
        }
    }
#undef LOADK
#undef LOADV

    // intra-wave lsum reduce over the 16 cols
    #pragma unroll
    for (int tt = 0; tt < 2; ++tt)
        #pragma unroll
        for (int r = 0; r < 4; ++r) {
            float v = lsum[tt][r];
            v += __shfl_xor(v, 1);
            v += __shfl_xor(v, 2);
            v += __shfl_xor(v, 4);
            v += __shfl_xor(v, 8);
            lsum[tt][r] = v;
        }

    // cross-wave combine (exact: everything is additive)
    if (wave > 0) {
        #pragma unroll
        for (int tt = 0; tt < 2; ++tt) {
            redbuf[wave - 1][lane][tt][0] = make_float4(o[tt][0][0], o[tt][0][1], o[tt][0][2], o[tt][0][3]);
            redbuf[wave - 1][lane][tt][1] = make_float4(o[tt][1][0], o[tt][1][1], o[tt][1][2], o[tt][1][3]);
            redbuf[wave - 1][lane][tt][2] = make_float4(o[tt][2][0], o[tt][2][1], o[tt][2][2], o[tt][2][3]);
            redbuf[wave - 1][lane][tt][3] = make_float4(o[tt][3][0], o[tt][3][1], o[tt][3][2], o[tt][3][3]);
            redbuf[wave - 1][lane][tt][4] = make_float4(lsum[tt][0], lsum[tt][1], lsum[tt][2], lsum[tt][3]);
        }
    }
    __syncthreads();
    if (wave == 0) {
        #pragma unroll
        for (int w = 0; w < 3; ++w)
            #pragma unroll
            for (int tt = 0; tt < 2; ++tt) {
                float4 t0 = redbuf[w][lane][tt][0];
                float4 t1 = redbuf[w][lane][tt][1];
                float4 t2 = redbuf[w][lane][tt][2];
                float4 t3 = redbuf[w][lane][tt][3];
                float4 tl = redbuf[w][lane][tt][4];
                o[tt][0][0] += t0.x; o[tt][0][1] += t0.y; o[tt][0][2] += t0.z; o[tt][0][3] += t0.w;
                o[tt][1][0] += t1.x; o[tt][1][1] += t1.y; o[tt][1][2] += t1.z; o[tt][1][3] += t1.w;
                o[tt][2][0] += t2.x; o[tt][2][1] += t2.y; o[tt][2][2] += t2.z; o[tt][2][3] += t2.w;
                o[tt][3][0] += t3.x; o[tt][3][1] += t3.y; o[tt][3][2] += t3.z; o[tt][3][3] += t3.w;
                lsum[tt][0] += tl.x; lsum[tt][1] += tl.y; lsum[tt][2] += tl.z; lsum[tt][3] += tl.w;
            }
        const int b = bh >> 4, h = bh & 15;
        #pragma unroll
        for (int tt = 0; tt < 2; ++tt)
            #pragma unroll
            for (int r = 0; r < 4; ++r) {
                float inv = 1.0f / lsum[tt][r];
                unsigned short* orow = attn + ((size_t)(b * SEQ + iR[tt][r])) * EMBD
                                            + h * HDIM + col;
                orow[0]  = f2bf(o[tt][0][r] * inv);
                orow[16] = f2bf(o[tt][1][r] * inv);
                orow[32] = f2bf(o[tt][2][r] * inv);
                orow[48] = f2bf(o[tt][3][r] * inv);
            }
    }
}

// ---------------------------------------------------------------------------
// Output projection: out = attn(bf16) @ w_out, LDS-free MFMA -> fp32.
// (EXACT R9 form -- best measured total.)
// ---------------------------------------------------------------------------
__global__ __launch_bounds__(256) void gemm_out_mfma(
    const unsigned short* __restrict__ A,      // [4096][1024] bf16
    const unsigned short* __restrict__ woT,    // [1024 n][1024 k] bf16
    float* __restrict__ out)
{
    const int t = threadIdx.x, wave = t >> 6, lane = t & 63;
    const int col = lane & 15, quad = lane >> 4;
    const int n0 = blockIdx.x * 128;
    const int m0 = blockIdx.y * 128;
    const int wm = (wave >> 1) * 64, wn = (wave & 1) * 64;

    floatx4 acc[4][4];
    #pragma unroll
    for (int i = 0; i < 4; ++i)
        #pragma unroll
        for (int j = 0; j < 4; ++j) acc[i][j] = (floatx4){0.f, 0.f, 0.f, 0.f};

    const unsigned short* pa = A   + (size_t)(m0 + wm + col) * 1024 + quad * 8;
    const unsigned short* pb = woT + (size_t)(n0 + wn + col) * 1024 + quad * 8;

    for (int k0 = 0; k0 < 1024; k0 += 32) {
        short8 af[4], bf[4];
        #pragma unroll
        for (int f = 0; f < 4; ++f) bf[f] = *(const short8*)(pb + f * 16 * 1024 + k0);
        #pragma unroll
        for (int f = 0; f < 4; ++f) af[f] = *(const short8*)(pa + f * 16 * 1024 + k0);
        #pragma unroll
        for (int fm = 0; fm < 4; ++fm)
            #pragma unroll
            for (int fn = 0; fn < 4; ++fn)
                acc[fm][fn] = __builtin_amdgcn_mfma_f32_16x16x32_bf16(
                    af[fm], bf[fn], acc[fm][fn], 0, 0, 0);
    }

    #pragma unroll
    for (int fm = 0; fm < 4; ++fm) {
        const int m = m0 + wm + fm * 16 + quad * 4;
        #pragma unroll
        for (int fn = 0; fn < 4; ++fn) {
            const int n = n0 + wn + fn * 16 + col;
            floatx4 c = acc[fm][fn];
            out[(size_t)(m + 0) * 1024 + n] = c[0];
            out[(size_t)(m + 1) * 1024 + n] = c[1];
            out[(size_t)(m + 2) * 1024 + n] = c[2];
            out[(size_t)(m + 3) * 1024 + n] = c[3];
        }
    }
}

// ---------------------------------------------------------------------------
extern "C" void kernel_launch(void* const* d_in, const int* in_sizes, int n_in,
                              void* d_out, int out_size, void* d_ws, size_t ws_size,
                              hipStream_t stream) {
    const float* x     = (const float*)d_in[0];  // (2,2048,1024)
    const float* w_qkv = (const float*)d_in[1];  // (1024,3072)
    const float* w_out = (const float*)d_in[2];  // (1024,1024)
    float* out = (float*)d_out;                  // (2,2048,1024)

    // Workspace map (bf16 elems; ~58.8 MB of the proven >=64 MB):
    unsigned short* ws16 = (unsigned short*)d_ws;
    unsigned short* xh  = ws16;              // 4,194,304
    unsigned short* xl  = ws16 +  4194304;   // 4,194,304
    unsigned short* wbT = ws16 +  8388608;   // 3,145,728  [3072][1024]
    unsigned short* woT = ws16 + 11534336;   // 1,048,576  [1024][1024]
    unsigned short* qst = ws16 + 12582912;   // 4,194,304  [bh][s][d]
    unsigned short* kst = ws16 + 16777216;   // 4,194,304  [bh][s][d]
    unsigned short* vtT = ws16 + 20971520;   // 4,227,072  [bh][d][VSTR] padded
    unsigned short* aws = ws16 + 25198592;   // 4,194,304  [M][E] bf16

    dim3 blk(256);
    cast_x<<<dim3(4096), blk, 0, stream>>>(x, xh, xl);
    cast_wT<<<dim3(48, 16), blk, 0, stream>>>(w_qkv, wbT, NQKV);
    cast_wT<<<dim3(16, 16), blk, 0, stream>>>(w_out, woT, EMBD);

    gemm_qkv_mfma<<<dim3(NQKV / 128, MROWS / 128), blk, 0, stream>>>(
        xh, xl, wbT, qst, kst, vtT);

    attn_mfma<<<dim3(32 * 64), blk, 0, stream>>>(qst, kst, vtT, aws);

    gemm_out_mfma<<<dim3(EMBD / 128, MROWS / 128), blk, 0, stream>>>(aws, woT, out);
}

// Round 15
// 357.215 us; speedup vs baseline: 1.3238x; 1.3238x over previous
//
#include <hip/hip_runtime.h>
#include <hip/hip_bf16.h>

// Problem constants
#define EMBD   1024
#define NHEAD  16
#define HDIM   64
#define SEQ    2048
#define BATCH  2
#define MROWS  4096          // BATCH*SEQ
#define NQKV   3072          // 3*EMBD
#define VSTR   2064          // padded vtT row stride (breaks 4KB L2 aliasing)

using floatx4 = __attribute__((ext_vector_type(4))) float;
using short8  = __attribute__((ext_vector_type(8))) short;

static __device__ __forceinline__ float bf2f(unsigned short u) {
    unsigned int v = ((unsigned int)u) << 16;
    return __uint_as_float(v);
}
static __device__ __forceinline__ unsigned short f2bf(float f) {
    __hip_bfloat16 h = __float2bfloat16(f);   // RNE
    return *reinterpret_cast<unsigned short*>(&h);
}

// ---------------------------------------------------------------------------
// Cast kernels: x -> split bf16 (hi + lo); w -> bf16, transposed to [N][K].
// ---------------------------------------------------------------------------
__global__ __launch_bounds__(256) void cast_x(
    const float* __restrict__ x, unsigned short* __restrict__ xh,
    unsigned short* __restrict__ xl)
{
    int idx = (blockIdx.x * 256 + threadIdx.x) * 4;
    float4 v = *(const float4*)(x + idx);
    ushort4 h, l;
    h.x = f2bf(v.x); l.x = f2bf(v.x - bf2f(h.x));
    h.y = f2bf(v.y); l.y = f2bf(v.y - bf2f(h.y));
    h.z = f2bf(v.z); l.z = f2bf(v.z - bf2f(h.z));
    h.w = f2bf(v.w); l.w = f2bf(v.w - bf2f(h.w));
    *(ushort4*)(xh + idx) = h;
    *(ushort4*)(xl + idx) = l;
}

// w [1024][N] fp32 -> wT [N][1024] bf16 (64x64 LDS-tiled transpose)
__global__ __launch_bounds__(256) void cast_wT(
    const float* __restrict__ w, unsigned short* __restrict__ wT, int N)
{
    __shared__ unsigned short th[64][65];
    const int k0 = blockIdx.y * 64, n0 = blockIdx.x * 64;
    const int t = threadIdx.x;
    const int r = t >> 4, c = (t & 15) * 4;
    for (int rr = r; rr < 64; rr += 16) {
        float4 v = *(const float4*)(w + (size_t)(k0 + rr) * N + n0 + c);
        th[rr][c + 0] = f2bf(v.x);
        th[rr][c + 1] = f2bf(v.y);
        th[rr][c + 2] = f2bf(v.z);
        th[rr][c + 3] = f2bf(v.w);
    }
    __syncthreads();
    for (int rr = r; rr < 64; rr += 16) {
        ushort4 h;
        h.x = th[c + 0][rr]; h.y = th[c + 1][rr];
        h.z = th[c + 2][rr]; h.w = th[c + 3][rr];
        *(ushort4*)(wT + (size_t)(n0 + rr) * 1024 + k0 + c) = h;
    }
}

// ---------------------------------------------------------------------------
// qkv = x @ w_qkv via split-x bf16 MFMA (xh.wb + xl.wb), fused RoPE.
// EXACT R9 form (best measured: 158 us, VGPR 124, WRITE ~93 MB).  Session
// verdict after 8 restructures (R3/R5/R7/R8/R9/R10/R11/R12/R14): every
// staging/pinning variant either sinks (no gain) or triggers 0.6-1.5 GB
// of pathological HBM writes (1.3-2.5x slower).  This form is the floor.
// ---------------------------------------------------------------------------
__global__ __launch_bounds__(256, 1) void gemm_qkv_mfma(
    const unsigned short* __restrict__ xh, const unsigned short* __restrict__ xl,
    const unsigned short* __restrict__ wbT,
    unsigned short* __restrict__ qst, unsigned short* __restrict__ kst,
    unsigned short* __restrict__ vtT)
{
    const int t = threadIdx.x, wave = t >> 6, lane = t & 63;
    const int col = lane & 15, quad = lane >> 4;
    const int n0 = blockIdx.x * 128;
    const int m0 = blockIdx.y * 128;
    const int which = n0 >> 10;              // block-uniform: 0=q,1=k,2=v
    const int wm = (wave >> 1) * 64, wn = (wave & 1) * 64;

    floatx4 acc[4][4];
    #pragma unroll
    for (int i = 0; i < 4; ++i)
        #pragma unroll
        for (int j = 0; j < 4; ++j) acc[i][j] = (floatx4){0.f, 0.f, 0.f, 0.f};

    const unsigned short* pa_h = xh  + (size_t)(m0 + wm + col) * 1024 + quad * 8;
    const unsigned short* pa_l = xl  + (size_t)(m0 + wm + col) * 1024 + quad * 8;
    const unsigned short* pb   = wbT + (size_t)(n0 + wn + col) * 1024 + quad * 8;

    short8 bfb[2][4], ahb[2][4], alb[2][4];   // double-buffered fragments

#define LOADQKV(B, K0) do {                                                       \
        _Pragma("unroll")                                                         \
        for (int f = 0; f < 4; ++f) bfb[B][f] = *(const short8*)(pb   + f * 16 * 1024 + (K0)); \
        _Pragma("unroll")                                                         \
        for (int f = 0; f < 4; ++f) ahb[B][f] = *(const short8*)(pa_h + f * 16 * 1024 + (K0)); \
        _Pragma("unroll")                                                         \
        for (int f = 0; f < 4; ++f) alb[B][f] = *(const short8*)(pa_l + f * 16 * 1024 + (K0)); \
    } while (0)

#define COMPUTE(B) do {                                                           \
        if (which < 2) {                                                          \
            _Pragma("unroll")                                                     \
            for (int fm = 0; fm < 4; ++fm)                                        \
                _Pragma("unroll")                                                 \
                for (int fn = 0; fn < 4; ++fn) {                                  \
                    acc[fm][fn] = __builtin_amdgcn_mfma_f32_16x16x32_bf16(        \
                        bfb[B][fn], ahb[B][fm], acc[fm][fn], 0, 0, 0);  /* C^T */ \
                    acc[fm][fn] = __builtin_amdgcn_mfma_f32_16x16x32_bf16(        \
                        bfb[B][fn], alb[B][fm], acc[fm][fn], 0, 0, 0);            \
                }                                                                 \
        } else {                                                                  \
            _Pragma("unroll")                                                     \
            for (int fm = 0; fm < 4; ++fm)                                        \
                _Pragma("unroll")                                                 \
                for (int fn = 0; fn < 4; ++fn) {                                  \
                    acc[fm][fn] = __builtin_amdgcn_mfma_f32_16x16x32_bf16(        \
                        ahb[B][fm], bfb[B][fn], acc[fm][fn], 0, 0, 0);            \
                    acc[fm][fn] = __builtin_amdgcn_mfma_f32_16x16x32_bf16(        \
                        alb[B][fm], bfb[B][fn], acc[fm][fn], 0, 0, 0);            \
                }                                                                 \
        }                                                                         \
    } while (0)

    LOADQKV(0, 0);
    for (int kk = 0; kk < 32; kk += 2) {
        LOADQKV(1, (kk + 1) * 32);                 // prefetch odd step
        COMPUTE(0);                                // even step
        if (kk + 2 < 32) LOADQKV(0, (kk + 2) * 32);  // prefetch next even
        COMPUTE(1);                                // odd step
    }
#undef LOADQKV
#undef COMPUTE

    const float RLOG = 9.210340371976184f / 32.0f;   // ln(10000)/32
    if (which < 2) {
        unsigned short* dst = (which == 0) ? qst : kst;
        const float scale = (which == 0) ? 0.125f : 1.0f;   // D^-0.5 folded into q
        #pragma unroll
        for (int fm = 0; fm < 4; ++fm) {
            const int s_g = m0 + wm + fm * 16 + col;     // C^T col = x row = s
            const int b = s_g >> 11, s = s_g & 2047;
            const float sf = (float)s;
            #pragma unroll
            for (int fn = 0; fn < 4; ++fn) {
                const int nl = (n0 & 1023) + wn + fn * 16 + quad * 4;  // C^T row = w col
                const int h = nl >> 6;
                const int d0 = nl & 63;                  // multiple of 4
                floatx4 c = acc[fm][fn];
                float o_[4];
                #pragma unroll
                for (int pp = 0; pp < 2; ++pp) {
                    int de = d0 + pp * 2;                // even
                    float fe = __expf(-(float)(de & 31) * RLOG);
                    float fo = __expf(-(float)((de + 1) & 31) * RLOG);
                    float se, ce, so, co;
                    sincosf(sf * fe, &se, &ce);
                    sincosf(sf * fo, &so, &co);
                    float qe = c[pp * 2], qo = c[pp * 2 + 1];
                    o_[pp * 2]     = (qe * ce - qo * se) * scale;
                    o_[pp * 2 + 1] = (qo * co + qe * so) * scale;
                }
                ushort4 o4;
                o4.x = f2bf(o_[0]); o4.y = f2bf(o_[1]);
                o4.z = f2bf(o_[2]); o4.w = f2bf(o_[3]);
                *(ushort4*)(dst + ((size_t)(b * 16 + h) * 2048 + s) * 64 + d0) = o4;
            }
        }
    } else {
        #pragma unroll
        for (int fm = 0; fm < 4; ++fm) {
            const int m = m0 + wm + fm * 16 + quad * 4;  // 4 consecutive s (regs)
            const int b = m >> 11, s0 = m & 2047;
            #pragma unroll
            for (int fn = 0; fn < 4; ++fn) {
                const int nl = (n0 & 1023) + wn + fn * 16 + col;
                const int h = nl >> 6;
                const int d = nl & 63;
                floatx4 c = acc[fm][fn];
                ushort4 o4;
                o4.x = f2bf(c[0]); o4.y = f2bf(c[1]);
                o4.z = f2bf(c[2]); o4.w = f2bf(c[3]);
                *(ushort4*)(vtT + (size_t)(b * 16 + h) * 64 * VSTR
                                + (size_t)d * VSTR + s0) = o4;
            }
        }
    }
}

// ---------------------------------------------------------------------------
// Attention (R4/R9 structure) + T1 XCD-GROUPING (the one new change):
// 2048 blocks = 32 bh x 64 row-units; default dispatch round-robins
// consecutive blocks across 8 XCDs, so each bh's 512 KB K/V is pulled into
// ALL EIGHT per-XCD L2s (FETCH 70 MB vs 24 MB ideal).  Bijective remap
// swz=(lin&7)*256+(lin>>3) puts each bh's 64 blocks on ONE XCD (4 bh/XCD,
// 2 MB < 4 MB L2): K/V loads become L2 hits (~200cy) instead of L3
// (~450cy) -- shortens the serial load chain of this latency-bound kernel.
// Block: 4 key-split waves x 32 rows (2 q-tiles/wave), padded p_tile.
// ---------------------------------------------------------------------------
__global__ __launch_bounds__(256) void attn_mfma(
    const unsigned short* __restrict__ qst,
    const unsigned short* __restrict__ kst,
    const unsigned short* __restrict__ vtT,
    unsigned short* __restrict__ attn)
{
    __shared__ __attribute__((aligned(16))) unsigned short p_tile[2][4][16][40];
    __shared__ float4 redbuf[3][64][2][5];         // waves 1..3 partials x 2 tiles

    const int tid  = threadIdx.x;
    const int wave = tid >> 6;
    const int lane = tid & 63;
    const int col  = lane & 15;
    const int quad = lane >> 4;

    // XCD grouping: 2048 = 8 XCDs x 256 blocks; same-bh blocks colocate.
    const int lin  = blockIdx.x;
    const int swz  = (lin & 7) * 256 + (lin >> 3);
    const int bh   = swz >> 6;                     // 0..31
    const int row0 = (swz & 63) * 32;              // 32-row unit (2 tiles)

    const size_t base  = (size_t)bh * SEQ * HDIM;
    const size_t vbase = (size_t)bh * HDIM * VSTR;

    // Q fragments for both tiles
    short8 aq[2][2];
    #pragma unroll
    for (int tt = 0; tt < 2; ++tt) {
        const unsigned short* qp = qst + base
            + (size_t)(row0 + tt * 16 + col) * HDIM + quad * 8;
        aq[tt][0] = *(const short8*)(qp);
        aq[tt][1] = *(const short8*)(qp + 32);
    }

    int iR[2][4], ngR[2][4], j0R[2][4];
    #pragma unroll
    for (int tt = 0; tt < 2; ++tt)
        #pragma unroll
        for (int r = 0; r < 4; ++r) {
            int i = row0 + tt * 16 + quad * 4 + r;
            iR[tt][r] = i;
            ngR[tt][r] = (i + 1 < 4) ? (i + 1) : 4;
            int L = i - 128;
            int bs = (i >> 8) << 8;
            if (bs < L) L = bs;
            if (L < 0) L = 0;
            j0R[tt][r] = (L > 4) ? L : 4;
        }

    floatx4 o[2][4];
    float lsum[2][4];
    #pragma unroll
    for (int tt = 0; tt < 2; ++tt)
        #pragma unroll
        for (int r = 0; r < 4; ++r) {
            o[tt][r] = (floatx4){0.f, 0.f, 0.f, 0.f};
            lsum[tt][r] = 0.f;
        }

    const int kbeg = wave * (SEQ / 4);             // 512 keys per wave

    // Double-buffered K/V fragments (indices static after full unroll).
    short8 kf[2][4];   // [buf][h16*2 + half]: K[kc+h16*16+col][quad*8 + half*32..]
    short8 vf[2][4];   // [buf][dt]:           V^T[d=col+16dt][kc+quad*8..]

#define LOADK(B, IT) do {                                                         \
        const int kc_ = kbeg + (IT) * 32;                                         \
        const unsigned short* kp_ = kst + base + (size_t)(kc_ + col) * HDIM       \
                                        + quad * 8;                               \
        kf[B][0] = *(const short8*)(kp_);                                         \
        kf[B][1] = *(const short8*)(kp_ + 32);                                    \
        kf[B][2] = *(const short8*)(kp_ + 16 * HDIM);                             \
        kf[B][3] = *(const short8*)(kp_ + 16 * HDIM + 32);                        \
    } while (0)
#define LOADV(B, IT) do {                                                         \
        const int kc_ = kbeg + (IT) * 32;                                         \
        const unsigned short* vp_ = vtT + vbase + (size_t)col * VSTR              \
                                        + kc_ + quad * 8;                         \
        vf[B][0] = *(const short8*)(vp_);                                         \
        vf[B][1] = *(const short8*)(vp_ + 16 * VSTR);                             \
        vf[B][2] = *(const short8*)(vp_ + 32 * VSTR);                             \
        vf[B][3] = *(const short8*)(vp_ + 48 * VSTR);                             \
    } while (0)

    LOADK(0, 0);
    LOADV(0, 0);
    #pragma unroll
    for (int it = 0; it < 16; ++it) {
        const int cur = it & 1;                    // compile-time after unroll
        if (it < 15) { LOADK(cur ^ 1, it + 1); LOADV(cur ^ 1, it + 1); }
        __builtin_amdgcn_sched_barrier(0);         // pin prefetch before compute

        const int kc0 = kbeg + it * 32;
        #pragma unroll
        for (int h16 = 0; h16 < 2; ++h16) {
            const int j = kc0 + h16 * 16 + col;
            #pragma unroll
            for (int tt = 0; tt < 2; ++tt) {
                floatx4 s = {0.f, 0.f, 0.f, 0.f};
                s = __builtin_amdgcn_mfma_f32_16x16x32_bf16(
                        aq[tt][0], kf[cur][h16 * 2 + 0], s, 0, 0, 0);
                s = __builtin_amdgcn_mfma_f32_16x16x32_bf16(
                        aq[tt][1], kf[cur][h16 * 2 + 1], s, 0, 0, 0);
                #pragma unroll
                for (int r = 0; r < 4; ++r) {
                    bool excl = (j < ngR[tt][r]) || (j >= j0R[tt][r] && j <= iR[tt][r]);
                    float p = excl ? 0.f : __expf(s[r]);
                    lsum[tt][r] += p;
                    p_tile[tt][wave][quad * 4 + r][h16 * 16 + col] = f2bf(p);
                }
            }
        }
        // wave-private LDS slices: no barrier (lgkmcnt-ordered)
        #pragma unroll
        for (int tt = 0; tt < 2; ++tt) {
            short8 ap = *(const short8*)&p_tile[tt][wave][col][quad * 8];
            o[tt][0] = __builtin_amdgcn_mfma_f32_16x16x32_bf16(ap, vf[cur][0], o[tt][0], 0, 0, 0);
            o[tt][1] = __builtin_amdgcn_mfma_f32_16x16x32_bf16(ap, vf[cur][1], o[tt][1], 0, 0, 0);
            o[tt][2] = __builtin_amdgcn_mfma_f32_16x16x32_bf16(ap, vf[cur][2], o[tt][2], 0, 0, 0);
            o[tt][3] = __builtin_amdgcn_mfma_f32_16x16x32_bf16(ap, vf[cur][3], o[tt][3], 0, 0, 0);
        }
    }
#undef LOADK
#undef LOADV

    // intra-wave lsum reduce over the 16 cols
    #pragma unroll
    for (int tt = 0; tt < 2; ++tt)
        #pragma unroll
        for (int r = 0; r < 4; ++r) {
            float v = lsum[tt][r];
            v += __shfl_xor(v, 1);
            v += __shfl_xor(v, 2);
            v += __shfl_xor(v, 4);
            v += __shfl_xor(v, 8);
            lsum[tt][r] = v;
        }

    // cross-wave combine (exact: everything is additive)
    if (wave > 0) {
        #pragma unroll
        for (int tt = 0; tt < 2; ++tt) {
            redbuf[wave - 1][lane][tt][0] = make_float4(o[tt][0][0], o[tt][0][1], o[tt][0][2], o[tt][0][3]);
            redbuf[wave - 1][lane][tt][1] = make_float4(o[tt][1][0], o[tt][1][1], o[tt][1][2], o[tt][1][3]);
            redbuf[wave - 1][lane][tt][2] = make_float4(o[tt][2][0], o[tt][2][1], o[tt][2][2], o[tt][2][3]);
            redbuf[wave - 1][lane][tt][3] = make_float4(o[tt][3][0], o[tt][3][1], o[tt][3][2], o[tt][3][3]);
            redbuf[wave - 1][lane][tt][4] = make_float4(lsum[tt][0], lsum[tt][1], lsum[tt][2], lsum[tt][3]);
        }
    }
    __syncthreads();
    if (wave == 0) {
        #pragma unroll
        for (int w = 0; w < 3; ++w)
            #pragma unroll
            for (int tt = 0; tt < 2; ++tt) {
                float4 t0 = redbuf[w][lane][tt][0];
                float4 t1 = redbuf[w][lane][tt][1];
                float4 t2 = redbuf[w][lane][tt][2];
                float4 t3 = redbuf[w][lane][tt][3];
                float4 tl = redbuf[w][lane][tt][4];
                o[tt][0][0] += t0.x; o[tt][0][1] += t0.y; o[tt][0][2] += t0.z; o[tt][0][3] += t0.w;
                o[tt][1][0] += t1.x; o[tt][1][1] += t1.y; o[tt][1][2] += t1.z; o[tt][1][3] += t1.w;
                o[tt][2][0] += t2.x; o[tt][2][1] += t2.y; o[tt][2][2] += t2.z; o[tt][2][3] += t2.w;
                o[tt][3][0] += t3.x; o[tt][3][1] += t3.y; o[tt][3][2] += t3.z; o[tt][3][3] += t3.w;
                lsum[tt][0] += tl.x; lsum[tt][1] += tl.y; lsum[tt][2] += tl.z; lsum[tt][3] += tl.w;
            }
        const int b = bh >> 4, h = bh & 15;
        #pragma unroll
        for (int tt = 0; tt < 2; ++tt)
            #pragma unroll
            for (int r = 0; r < 4; ++r) {
                float inv = 1.0f / lsum[tt][r];
                unsigned short* orow = attn + ((size_t)(b * SEQ + iR[tt][r])) * EMBD
                                            + h * HDIM + col;
                orow[0]  = f2bf(o[tt][0][r] * inv);
                orow[16] = f2bf(o[tt][1][r] * inv);
                orow[32] = f2bf(o[tt][2][r] * inv);
                orow[48] = f2bf(o[tt][3][r] * inv);
            }
    }
}

// ---------------------------------------------------------------------------
// Output projection: out = attn(bf16) @ w_out, LDS-free MFMA -> fp32.
// (EXACT R9 form -- best measured total.)
// ---------------------------------------------------------------------------
__global__ __launch_bounds__(256) void gemm_out_mfma(
    const unsigned short* __restrict__ A,      // [4096][1024] bf16
    const unsigned short* __restrict__ woT,    // [1024 n][1024 k] bf16
    float* __restrict__ out)
{
    const int t = threadIdx.x, wave = t >> 6, lane = t & 63;
    const int col = lane & 15, quad = lane >> 4;
    const int n0 = blockIdx.x * 128;
    const int m0 = blockIdx.y * 128;
    const int wm = (wave >> 1) * 64, wn = (wave & 1) * 64;

    floatx4 acc[4][4];
    #pragma unroll
    for (int i = 0; i < 4; ++i)
        #pragma unroll
        for (int j = 0; j < 4; ++j) acc[i][j] = (floatx4){0.f, 0.f, 0.f, 0.f};

    const unsigned short* pa = A   + (size_t)(m0 + wm + col) * 1024 + quad * 8;
    const unsigned short* pb = woT + (size_t)(n0 + wn + col) * 1024 + quad * 8;

    for (int k0 = 0; k0 < 1024; k0 += 32) {
        short8 af[4], bf[4];
        #pragma unroll
        for (int f = 0; f < 4; ++f) bf[f] = *(const short8*)(pb + f * 16 * 1024 + k0);
        #pragma unroll
        for (int f = 0; f < 4; ++f) af[f] = *(const short8*)(pa + f * 16 * 1024 + k0);
        #pragma unroll
        for (int fm = 0; fm < 4; ++fm)
            #pragma unroll
            for (int fn = 0; fn < 4; ++fn)
                acc[fm][fn] = __builtin_amdgcn_mfma_f32_16x16x32_bf16(
                    af[fm], bf[fn], acc[fm][fn], 0, 0, 0);
    }

    #pragma unroll
    for (int fm = 0; fm < 4; ++fm) {
        const int m = m0 + wm + fm * 16 + quad * 4;
        #pragma unroll
        for (int fn = 0; fn < 4; ++fn) {
            const int n = n0 + wn + fn * 16 + col;
            floatx4 c = acc[fm][fn];
            out[(size_t)(m + 0) * 1024 + n] = c[0];
            out[(size_t)(m + 1) * 1024 + n] = c[1];
            out[(size_t)(m + 2) * 1024 + n] = c[2];
            out[(size_t)(m + 3) * 1024 + n] = c[3];
        }
    }
}

// ---------------------------------------------------------------------------
extern "C" void kernel_launch(void* const* d_in, const int* in_sizes, int n_in,
                              void* d_out, int out_size, void* d_ws, size_t ws_size,
                              hipStream_t stream) {
    const float* x     = (const float*)d_in[0];  // (2,2048,1024)
    const float* w_qkv = (const float*)d_in[1];  // (1024,3072)
    const float* w_out = (const float*)d_in[2];  // (1024,1024)
    float* out = (float*)d_out;                  // (2,2048,1024)

    // Workspace map (bf16 elems; ~58.8 MB of the proven >=64 MB):
    unsigned short* ws16 = (unsigned short*)d_ws;
    unsigned short* xh  = ws16;              // 4,194,304
    unsigned short* xl  = ws16 +  4194304;   // 4,194,304
    unsigned short* wbT = ws16 +  8388608;   // 3,145,728  [3072][1024]
    unsigned short* woT = ws16 + 11534336;   // 1,048,576  [1024][1024]
    unsigned short* qst = ws16 + 12582912;   // 4,194,304  [bh][s][d]
    unsigned short* kst = ws16 + 16777216;   // 4,194,304  [bh][s][d]
    unsigned short* vtT = ws16 + 20971520;   // 4,227,072  [bh][d][VSTR] padded
    unsigned short* aws = ws16 + 25198592;   // 4,194,304  [M][E] bf16

    dim3 blk(256);
    cast_x<<<dim3(4096), blk, 0, stream>>>(x, xh, xl);
    cast_wT<<<dim3(48, 16), blk, 0, stream>>>(w_qkv, wbT, NQKV);
    cast_wT<<<dim3(16, 16), blk, 0, stream>>>(w_out, woT, EMBD);

    gemm_qkv_mfma<<<dim3(NQKV / 128, MROWS / 128), blk, 0, stream>>>(
        xh, xl, wbT, qst, kst, vtT);

    attn_mfma<<<dim3(32 * 64), blk, 0, stream>>>(qst, kst, vtT, aws);

    gemm_out_mfma<<<dim3(EMBD / 128, MROWS / 128), blk, 0, stream>>>(aws, woT, out);
}

// Round 16
// 356.503 us; speedup vs baseline: 1.3265x; 1.0020x over previous
//
#include <hip/hip_runtime.h>
#include <hip/hip_bf16.h>

// Problem constants
#define EMBD   1024
#define NHEAD  16
#define HDIM   64
#define SEQ    2048
#define BATCH  2
#define MROWS  4096          // BATCH*SEQ
#define NQKV   3072          // 3*EMBD
#define VSTR   2064          // padded vtT row stride (breaks 4KB L2 aliasing)

using floatx4 = __attribute__((ext_vector_type(4))) float;
using short8  = __attribute__((ext_vector_type(8))) short;

static __device__ __forceinline__ float bf2f(unsigned short u) {
    unsigned int v = ((unsigned int)u) << 16;
    return __uint_as_float(v);
}
static __device__ __forceinline__ unsigned short f2bf(float f) {
    __hip_bfloat16 h = __float2bfloat16(f);   // RNE
    return *reinterpret_cast<unsigned short*>(&h);
}

// ---------------------------------------------------------------------------
// Cast kernels: x -> split bf16 (hi + lo); w -> bf16, transposed to [N][K].
// ---------------------------------------------------------------------------
__global__ __launch_bounds__(256) void cast_x(
    const float* __restrict__ x, unsigned short* __restrict__ xh,
    unsigned short* __restrict__ xl)
{
    int idx = (blockIdx.x * 256 + threadIdx.x) * 4;
    float4 v = *(const float4*)(x + idx);
    ushort4 h, l;
    h.x = f2bf(v.x); l.x = f2bf(v.x - bf2f(h.x));
    h.y = f2bf(v.y); l.y = f2bf(v.y - bf2f(h.y));
    h.z = f2bf(v.z); l.z = f2bf(v.z - bf2f(h.z));
    h.w = f2bf(v.w); l.w = f2bf(v.w - bf2f(h.w));
    *(ushort4*)(xh + idx) = h;
    *(ushort4*)(xl + idx) = l;
}

// w [1024][N] fp32 -> wT [N][1024] bf16 (64x64 LDS-tiled transpose)
__global__ __launch_bounds__(256) void cast_wT(
    const float* __restrict__ w, unsigned short* __restrict__ wT, int N)
{
    __shared__ unsigned short th[64][65];
    const int k0 = blockIdx.y * 64, n0 = blockIdx.x * 64;
    const int t = threadIdx.x;
    const int r = t >> 4, c = (t & 15) * 4;
    for (int rr = r; rr < 64; rr += 16) {
        float4 v = *(const float4*)(w + (size_t)(k0 + rr) * N + n0 + c);
        th[rr][c + 0] = f2bf(v.x);
        th[rr][c + 1] = f2bf(v.y);
        th[rr][c + 2] = f2bf(v.z);
        th[rr][c + 3] = f2bf(v.w);
    }
    __syncthreads();
    for (int rr = r; rr < 64; rr += 16) {
        ushort4 h;
        h.x = th[c + 0][rr]; h.y = th[c + 1][rr];
        h.z = th[c + 2][rr]; h.w = th[c + 3][rr];
        *(ushort4*)(wT + (size_t)(n0 + rr) * 1024 + k0 + c) = h;
    }
}

// ---------------------------------------------------------------------------
// qkv = x @ w_qkv via split-x bf16 MFMA (xh.wb + xl.wb), fused RoPE.
// EXACT R9 form (best measured: 157 us, VGPR 124).  Session verdict after
// 8 restructures: every staging/pinning variant either sinks (no gain) or
// triggers 0.6-1.5 GB of pathological HBM writes.  This form is the floor.
// ---------------------------------------------------------------------------
__global__ __launch_bounds__(256, 1) void gemm_qkv_mfma(
    const unsigned short* __restrict__ xh, const unsigned short* __restrict__ xl,
    const unsigned short* __restrict__ wbT,
    unsigned short* __restrict__ qst, unsigned short* __restrict__ kst,
    unsigned short* __restrict__ vtT)
{
    const int t = threadIdx.x, wave = t >> 6, lane = t & 63;
    const int col = lane & 15, quad = lane >> 4;
    const int n0 = blockIdx.x * 128;
    const int m0 = blockIdx.y * 128;
    const int which = n0 >> 10;              // block-uniform: 0=q,1=k,2=v
    const int wm = (wave >> 1) * 64, wn = (wave & 1) * 64;

    floatx4 acc[4][4];
    #pragma unroll
    for (int i = 0; i < 4; ++i)
        #pragma unroll
        for (int j = 0; j < 4; ++j) acc[i][j] = (floatx4){0.f, 0.f, 0.f, 0.f};

    const unsigned short* pa_h = xh  + (size_t)(m0 + wm + col) * 1024 + quad * 8;
    const unsigned short* pa_l = xl  + (size_t)(m0 + wm + col) * 1024 + quad * 8;
    const unsigned short* pb   = wbT + (size_t)(n0 + wn + col) * 1024 + quad * 8;

    short8 bfb[2][4], ahb[2][4], alb[2][4];   // double-buffered fragments

#define LOADQKV(B, K0) do {                                                       \
        _Pragma("unroll")                                                         \
        for (int f = 0; f < 4; ++f) bfb[B][f] = *(const short8*)(pb   + f * 16 * 1024 + (K0)); \
        _Pragma("unroll")                                                         \
        for (int f = 0; f < 4; ++f) ahb[B][f] = *(const short8*)(pa_h + f * 16 * 1024 + (K0)); \
        _Pragma("unroll")                                                         \
        for (int f = 0; f < 4; ++f) alb[B][f] = *(const short8*)(pa_l + f * 16 * 1024 + (K0)); \
    } while (0)

#define COMPUTE(B) do {                                                           \
        if (which < 2) {                                                          \
            _Pragma("unroll")                                                     \
            for (int fm = 0; fm < 4; ++fm)                                        \
                _Pragma("unroll")                                                 \
                for (int fn = 0; fn < 4; ++fn) {                                  \
                    acc[fm][fn] = __builtin_amdgcn_mfma_f32_16x16x32_bf16(        \
                        bfb[B][fn], ahb[B][fm], acc[fm][fn], 0, 0, 0);  /* C^T */ \
                    acc[fm][fn] = __builtin_amdgcn_mfma_f32_16x16x32_bf16(        \
                        bfb[B][fn], alb[B][fm], acc[fm][fn], 0, 0, 0);            \
                }                                                                 \
        } else {                                                                  \
            _Pragma("unroll")                                                     \
            for (int fm = 0; fm < 4; ++fm)                                        \
                _Pragma("unroll")                                                 \
                for (int fn = 0; fn < 4; ++fn) {                                  \
                    acc[fm][fn] = __builtin_amdgcn_mfma_f32_16x16x32_bf16(        \
                        ahb[B][fm], bfb[B][fn], acc[fm][fn], 0, 0, 0);            \
                    acc[fm][fn] = __builtin_amdgcn_mfma_f32_16x16x32_bf16(        \
                        alb[B][fm], bfb[B][fn], acc[fm][fn], 0, 0, 0);            \
                }                                                                 \
        }                                                                         \
    } while (0)

    LOADQKV(0, 0);
    for (int kk = 0; kk < 32; kk += 2) {
        LOADQKV(1, (kk + 1) * 32);                 // prefetch odd step
        COMPUTE(0);                                // even step
        if (kk + 2 < 32) LOADQKV(0, (kk + 2) * 32);  // prefetch next even
        COMPUTE(1);                                // odd step
    }
#undef LOADQKV
#undef COMPUTE

    const float RLOG = 9.210340371976184f / 32.0f;   // ln(10000)/32
    if (which < 2) {
        unsigned short* dst = (which == 0) ? qst : kst;
        const float scale = (which == 0) ? 0.125f : 1.0f;   // D^-0.5 folded into q
        #pragma unroll
        for (int fm = 0; fm < 4; ++fm) {
            const int s_g = m0 + wm + fm * 16 + col;     // C^T col = x row = s
            const int b = s_g >> 11, s = s_g & 2047;
            const float sf = (float)s;
            #pragma unroll
            for (int fn = 0; fn < 4; ++fn) {
                const int nl = (n0 & 1023) + wn + fn * 16 + quad * 4;  // C^T row = w col
                const int h = nl >> 6;
                const int d0 = nl & 63;                  // multiple of 4
                floatx4 c = acc[fm][fn];
                float o_[4];
                #pragma unroll
                for (int pp = 0; pp < 2; ++pp) {
                    int de = d0 + pp * 2;                // even
                    float fe = __expf(-(float)(de & 31) * RLOG);
                    float fo = __expf(-(float)((de + 1) & 31) * RLOG);
                    float se, ce, so, co;
                    sincosf(sf * fe, &se, &ce);
                    sincosf(sf * fo, &so, &co);
                    float qe = c[pp * 2], qo = c[pp * 2 + 1];
                    o_[pp * 2]     = (qe * ce - qo * se) * scale;
                    o_[pp * 2 + 1] = (qo * co + qe * so) * scale;
                }
                ushort4 o4;
                o4.x = f2bf(o_[0]); o4.y = f2bf(o_[1]);
                o4.z = f2bf(o_[2]); o4.w = f2bf(o_[3]);
                *(ushort4*)(dst + ((size_t)(b * 16 + h) * 2048 + s) * 64 + d0) = o4;
            }
        }
    } else {
        #pragma unroll
        for (int fm = 0; fm < 4; ++fm) {
            const int m = m0 + wm + fm * 16 + quad * 4;  // 4 consecutive s (regs)
            const int b = m >> 11, s0 = m & 2047;
            #pragma unroll
            for (int fn = 0; fn < 4; ++fn) {
                const int nl = (n0 & 1023) + wn + fn * 16 + col;
                const int h = nl >> 6;
                const int d = nl & 63;
                floatx4 c = acc[fm][fn];
                ushort4 o4;
                o4.x = f2bf(c[0]); o4.y = f2bf(c[1]);
                o4.z = f2bf(c[2]); o4.w = f2bf(c[3]);
                *(ushort4*)(vtT + (size_t)(b * 16 + h) * 64 * VSTR
                                + (size_t)d * VSTR + s0) = o4;
            }
        }
    }
}

// ---------------------------------------------------------------------------
// Attention (R15 form, verified best): R4/R9 structure + T1 XCD-grouping
// (each bh's 64 blocks colocate on one XCD; K/V becomes L2-resident).
// Block: 4 key-split waves x 32 rows (2 q-tiles/wave), padded p_tile.
// ---------------------------------------------------------------------------
__global__ __launch_bounds__(256) void attn_mfma(
    const unsigned short* __restrict__ qst,
    const unsigned short* __restrict__ kst,
    const unsigned short* __restrict__ vtT,
    unsigned short* __restrict__ attn)
{
    __shared__ __attribute__((aligned(16))) unsigned short p_tile[2][4][16][40];
    __shared__ float4 redbuf[3][64][2][5];         // waves 1..3 partials x 2 tiles

    const int tid  = threadIdx.x;
    const int wave = tid >> 6;
    const int lane = tid & 63;
    const int col  = lane & 15;
    const int quad = lane >> 4;

    // XCD grouping: 2048 = 8 XCDs x 256 blocks; same-bh blocks colocate.
    const int lin  = blockIdx.x;
    const int swz  = (lin & 7) * 256 + (lin >> 3);
    const int bh   = swz >> 6;                     // 0..31
    const int row0 = (swz & 63) * 32;              // 32-row unit (2 tiles)

    const size_t base  = (size_t)bh * SEQ * HDIM;
    const size_t vbase = (size_t)bh * HDIM * VSTR;

    // Q fragments for both tiles
    short8 aq[2][2];
    #pragma unroll
    for (int tt = 0; tt < 2; ++tt) {
        const unsigned short* qp = qst + base
            + (size_t)(row0 + tt * 16 + col) * HDIM + quad * 8;
        aq[tt][0] = *(const short8*)(qp);
        aq[tt][1] = *(const short8*)(qp + 32);
    }

    int iR[2][4], ngR[2][4], j0R[2][4];
    #pragma unroll
    for (int tt = 0; tt < 2; ++tt)
        #pragma unroll
        for (int r = 0; r < 4; ++r) {
            int i = row0 + tt * 16 + quad * 4 + r;
            iR[tt][r] = i;
            ngR[tt][r] = (i + 1 < 4) ? (i + 1) : 4;
            int L = i - 128;
            int bs = (i >> 8) << 8;
            if (bs < L) L = bs;
            if (L < 0) L = 0;
            j0R[tt][r] = (L > 4) ? L : 4;
        }

    floatx4 o[2][4];
    float lsum[2][4];
    #pragma unroll
    for (int tt = 0; tt < 2; ++tt)
        #pragma unroll
        for (int r = 0; r < 4; ++r) {
            o[tt][r] = (floatx4){0.f, 0.f, 0.f, 0.f};
            lsum[tt][r] = 0.f;
        }

    const int kbeg = wave * (SEQ / 4);             // 512 keys per wave

    // Double-buffered K/V fragments (indices static after full unroll).
    short8 kf[2][4];   // [buf][h16*2 + half]: K[kc+h16*16+col][quad*8 + half*32..]
    short8 vf[2][4];   // [buf][dt]:           V^T[d=col+16dt][kc+quad*8..]

#define LOADK(B, IT) do {                                                         \
        const int kc_ = kbeg + (IT) * 32;                                         \
        const unsigned short* kp_ = kst + base + (size_t)(kc_ + col) * HDIM       \
                                        + quad * 8;                               \
        kf[B][0] = *(const short8*)(kp_);                                         \
        kf[B][1] = *(const short8*)(kp_ + 32);                                    \
        kf[B][2] = *(const short8*)(kp_ + 16 * HDIM);                             \
        kf[B][3] = *(const short8*)(kp_ + 16 * HDIM + 32);                        \
    } while (0)
#define LOADV(B, IT) do {                                                         \
        const int kc_ = kbeg + (IT) * 32;                                         \
        const unsigned short* vp_ = vtT + vbase + (size_t)col * VSTR              \
                                        + kc_ + quad * 8;                         \
        vf[B][0] = *(const short8*)(vp_);                                         \
        vf[B][1] = *(const short8*)(vp_ + 16 * VSTR);                             \
        vf[B][2] = *(const short8*)(vp_ + 32 * VSTR);                             \
        vf[B][3] = *(const short8*)(vp_ + 48 * VSTR);                             \
    } while (0)

    LOADK(0, 0);
    LOADV(0, 0);
    #pragma unroll
    for (int it = 0; it < 16; ++it) {
        const int cur = it & 1;                    // compile-time after unroll
        if (it < 15) { LOADK(cur ^ 1, it + 1); LOADV(cur ^ 1, it + 1); }
        __builtin_amdgcn_sched_barrier(0);         // pin prefetch before compute

        const int kc0 = kbeg + it * 32;
        #pragma unroll
        for (int h16 = 0; h16 < 2; ++h16) {
            const int j = kc0 + h16 * 16 + col;
            #pragma unroll
            for (int tt = 0; tt < 2; ++tt) {
                floatx4 s = {0.f, 0.f, 0.f, 0.f};
                s = __builtin_amdgcn_mfma_f32_16x16x32_bf16(
                        aq[tt][0], kf[cur][h16 * 2 + 0], s, 0, 0, 0);
                s = __builtin_amdgcn_mfma_f32_16x16x32_bf16(
                        aq[tt][1], kf[cur][h16 * 2 + 1], s, 0, 0, 0);
                #pragma unroll
                for (int r = 0; r < 4; ++r) {
                    bool excl = (j < ngR[tt][r]) || (j >= j0R[tt][r] && j <= iR[tt][r]);
                    float p = excl ? 0.f : __expf(s[r]);
                    lsum[tt][r] += p;
                    p_tile[tt][wave][quad * 4 + r][h16 * 16 + col] = f2bf(p);
                }
            }
        }
        // wave-private LDS slices: no barrier (lgkmcnt-ordered)
        #pragma unroll
        for (int tt = 0; tt < 2; ++tt) {
            short8 ap = *(const short8*)&p_tile[tt][wave][col][quad * 8];
            o[tt][0] = __builtin_amdgcn_mfma_f32_16x16x32_bf16(ap, vf[cur][0], o[tt][0], 0, 0, 0);
            o[tt][1] = __builtin_amdgcn_mfma_f32_16x16x32_bf16(ap, vf[cur][1], o[tt][1], 0, 0, 0);
            o[tt][2] = __builtin_amdgcn_mfma_f32_16x16x32_bf16(ap, vf[cur][2], o[tt][2], 0, 0, 0);
            o[tt][3] = __builtin_amdgcn_mfma_f32_16x16x32_bf16(ap, vf[cur][3], o[tt][3], 0, 0, 0);
        }
    }
#undef LOADK
#undef LOADV

    // intra-wave lsum reduce over the 16 cols
    #pragma unroll
    for (int tt = 0; tt < 2; ++tt)
        #pragma unroll
        for (int r = 0; r < 4; ++r) {
            float v = lsum[tt][r];
            v += __shfl_xor(v, 1);
            v += __shfl_xor(v, 2);
            v += __shfl_xor(v, 4);
            v += __shfl_xor(v, 8);
            lsum[tt][r] = v;
        }

    // cross-wave combine (exact: everything is additive)
    if (wave > 0) {
        #pragma unroll
        for (int tt = 0; tt < 2; ++tt) {
            redbuf[wave - 1][lane][tt][0] = make_float4(o[tt][0][0], o[tt][0][1], o[tt][0][2], o[tt][0][3]);
            redbuf[wave - 1][lane][tt][1] = make_float4(o[tt][1][0], o[tt][1][1], o[tt][1][2], o[tt][1][3]);
            redbuf[wave - 1][lane][tt][2] = make_float4(o[tt][2][0], o[tt][2][1], o[tt][2][2], o[tt][2][3]);
            redbuf[wave - 1][lane][tt][3] = make_float4(o[tt][3][0], o[tt][3][1], o[tt][3][2], o[tt][3][3]);
            redbuf[wave - 1][lane][tt][4] = make_float4(lsum[tt][0], lsum[tt][1], lsum[tt][2], lsum[tt][3]);
        }
    }
    __syncthreads();
    if (wave == 0) {
        #pragma unroll
        for (int w = 0; w < 3; ++w)
            #pragma unroll
            for (int tt = 0; tt < 2; ++tt) {
                float4 t0 = redbuf[w][lane][tt][0];
                float4 t1 = redbuf[w][lane][tt][1];
                float4 t2 = redbuf[w][lane][tt][2];
                float4 t3 = redbuf[w][lane][tt][3];
                float4 tl = redbuf[w][lane][tt][4];
                o[tt][0][0] += t0.x; o[tt][0][1] += t0.y; o[tt][0][2] += t0.z; o[tt][0][3] += t0.w;
                o[tt][1][0] += t1.x; o[tt][1][1] += t1.y; o[tt][1][2] += t1.z; o[tt][1][3] += t1.w;
                o[tt][2][0] += t2.x; o[tt][2][1] += t2.y; o[tt][2][2] += t2.z; o[tt][2][3] += t2.w;
                o[tt][3][0] += t3.x; o[tt][3][1] += t3.y; o[tt][3][2] += t3.z; o[tt][3][3] += t3.w;
                lsum[tt][0] += tl.x; lsum[tt][1] += tl.y; lsum[tt][2] += tl.z; lsum[tt][3] += tl.w;
            }
        const int b = bh >> 4, h = bh & 15;
        #pragma unroll
        for (int tt = 0; tt < 2; ++tt)
            #pragma unroll
            for (int r = 0; r < 4; ++r) {
                float inv = 1.0f / lsum[tt][r];
                unsigned short* orow = attn + ((size_t)(b * SEQ + iR[tt][r])) * EMBD
                                            + h * HDIM + col;
                orow[0]  = f2bf(o[tt][0][r] * inv);
                orow[16] = f2bf(o[tt][1][r] * inv);
                orow[32] = f2bf(o[tt][2][r] * inv);
                orow[48] = f2bf(o[tt][3][r] * inv);
            }
    }
}

// ---------------------------------------------------------------------------
// Output projection: out = attn(bf16) @ w_out, LDS-free MFMA -> fp32.
// v4 = R9 body + T1 XCD-GROUPING (the one new change this round).
// 256 blocks = 1 block/CU, latency-bound.  Grid (8,32): the 8 n-blocks
// sharing each 256 KB A-panel were round-robined across all 8 XCDs ->
// every A-panel pulled into all eight L2s from L3.  Remap: XCD x owns
// m-panels 4x..4x+3 (1 MB A + 2 MB woT = 3 MB < 4 MB L2) -> A loads hit
// own-XCD L2 (~200cy) instead of L3 (~450cy); at 1 wave/SIMD the chain
// shortening maps ~1:1 to time.
// ---------------------------------------------------------------------------
__global__ __launch_bounds__(256) void gemm_out_mfma(
    const unsigned short* __restrict__ A,      // [4096][1024] bf16
    const unsigned short* __restrict__ woT,    // [1024 n][1024 k] bf16
    float* __restrict__ out)
{
    const int t = threadIdx.x, wave = t >> 6, lane = t & 63;
    const int col = lane & 15, quad = lane >> 4;
    // XCD grouping: 256 = 8 XCDs x 32; XCD x gets swz 32x..32x+31 ->
    // m-blocks 4x..4x+3, all 8 n-blocks each.
    const int lin = blockIdx.x;
    const int swz = (lin & 7) * 32 + (lin >> 3);
    const int n0 = (swz & 7) * 128;
    const int m0 = (swz >> 3) * 128;
    const int wm = (wave >> 1) * 64, wn = (wave & 1) * 64;

    floatx4 acc[4][4];
    #pragma unroll
    for (int i = 0; i < 4; ++i)
        #pragma unroll
        for (int j = 0; j < 4; ++j) acc[i][j] = (floatx4){0.f, 0.f, 0.f, 0.f};

    const unsigned short* pa = A   + (size_t)(m0 + wm + col) * 1024 + quad * 8;
    const unsigned short* pb = woT + (size_t)(n0 + wn + col) * 1024 + quad * 8;

    for (int k0 = 0; k0 < 1024; k0 += 32) {
        short8 af[4], bf[4];
        #pragma unroll
        for (int f = 0; f < 4; ++f) bf[f] = *(const short8*)(pb + f * 16 * 1024 + k0);
        #pragma unroll
        for (int f = 0; f < 4; ++f) af[f] = *(const short8*)(pa + f * 16 * 1024 + k0);
        #pragma unroll
        for (int fm = 0; fm < 4; ++fm)
            #pragma unroll
            for (int fn = 0; fn < 4; ++fn)
                acc[fm][fn] = __builtin_amdgcn_mfma_f32_16x16x32_bf16(
                    af[fm], bf[fn], acc[fm][fn], 0, 0, 0);
    }

    #pragma unroll
    for (int fm = 0; fm < 4; ++fm) {
        const int m = m0 + wm + fm * 16 + quad * 4;
        #pragma unroll
        for (int fn = 0; fn < 4; ++fn) {
            const int n = n0 + wn + fn * 16 + col;
            floatx4 c = acc[fm][fn];
            out[(size_t)(m + 0) * 1024 + n] = c[0];
            out[(size_t)(m + 1) * 1024 + n] = c[1];
            out[(size_t)(m + 2) * 1024 + n] = c[2];
            out[(size_t)(m + 3) * 1024 + n] = c[3];
        }
    }
}

// ---------------------------------------------------------------------------
extern "C" void kernel_launch(void* const* d_in, const int* in_sizes, int n_in,
                              void* d_out, int out_size, void* d_ws, size_t ws_size,
                              hipStream_t stream) {
    const float* x     = (const float*)d_in[0];  // (2,2048,1024)
    const float* w_qkv = (const float*)d_in[1];  // (1024,3072)
    const float* w_out = (const float*)d_in[2];  // (1024,1024)
    float* out = (float*)d_out;                  // (2,2048,1024)

    // Workspace map (bf16 elems; ~58.8 MB of the proven >=64 MB):
    unsigned short* ws16 = (unsigned short*)d_ws;
    unsigned short* xh  = ws16;              // 4,194,304
    unsigned short* xl  = ws16 +  4194304;   // 4,194,304
    unsigned short* wbT = ws16 +  8388608;   // 3,145,728  [3072][1024]
    unsigned short* woT = ws16 + 11534336;   // 1,048,576  [1024][1024]
    unsigned short* qst = ws16 + 12582912;   // 4,194,304  [bh][s][d]
    unsigned short* kst = ws16 + 16777216;   // 4,194,304  [bh][s][d]
    unsigned short* vtT = ws16 + 20971520;   // 4,227,072  [bh][d][VSTR] padded
    unsigned short* aws = ws16 + 25198592;   // 4,194,304  [M][E] bf16

    dim3 blk(256);
    cast_x<<<dim3(4096), blk, 0, stream>>>(x, xh, xl);
    cast_wT<<<dim3(48, 16), blk, 0, stream>>>(w_qkv, wbT, NQKV);
    cast_wT<<<dim3(16, 16), blk, 0, stream>>>(w_out, woT, EMBD);

    gemm_qkv_mfma<<<dim3(NQKV / 128, MROWS / 128), blk, 0, stream>>>(
        xh, xl, wbT, qst, kst, vtT);

    attn_mfma<<<dim3(32 * 64), blk, 0, stream>>>(qst, kst, vtT, aws);

    gemm_out_mfma<<<dim3(256), blk, 0, stream>>>(aws, woT, out);
}